// Round 1
// baseline (98.394 us; speedup 1.0000x reference)
//
#include <hip/hip_runtime.h>

#define N_POINTS 204800
#define N_GT 256

// Precompute per-box quadratic coefficients into d_ws (8 floats/box, 16B-aligned):
//   fx(px) = (px-x1)(x2-px)/w = a2x*px^2 + a1x*px + a0x   with w = x2-x1
//   a2x = -1/w, a1x = (x1+x2)/w, a0x = -(x1*x2)/w         (same for y with h)
// centerness(point, box) = sqrt(max(fx,0) * max(fy,0)); out = max over boxes.
// sqrt hoisted out of the max (monotone). Division folded into coefficients
// (valid: when point is outside, numerator is exactly 0 regardless of denom).
__global__ __launch_bounds__(256) void box_coef_kernel(
    const float* __restrict__ gt, float* __restrict__ coef) {
    int j = threadIdx.x;  // one block of 256, one thread per box
    float x1 = gt[4 * j + 0];
    float y1 = gt[4 * j + 1];
    float x2 = gt[4 * j + 2];
    float y2 = gt[4 * j + 3];
    float iw = 1.0f / (x2 - x1);
    float ih = 1.0f / (y2 - y1);
    float* c = coef + 8 * j;
    c[0] = -iw;
    c[1] = (x1 + x2) * iw;
    c[2] = -(x1 * x2) * iw;
    c[3] = 0.0f;
    c[4] = -ih;
    c[5] = (y1 + y2) * ih;
    c[6] = -(y1 * y2) * ih;
    c[7] = 0.0f;
}

__global__ __launch_bounds__(256) void centerness_kernel(
    const float* __restrict__ points, const float* __restrict__ coef,
    float* __restrict__ out) {
    int i = blockIdx.x * 256 + threadIdx.x;  // grid covers exactly N_POINTS
    float2 p = ((const float2*)points)[i];
    float px = p.x, py = p.y;

    const float4* __restrict__ c4 = (const float4*)coef;

    // 4 accumulators to break the 256-deep max dependence chain.
    float acc0 = 0.0f, acc1 = 0.0f, acc2 = 0.0f, acc3 = 0.0f;

#pragma unroll 8
    for (int j = 0; j < N_GT; j += 4) {
        float4 cx0 = c4[2 * j + 0];
        float4 cy0 = c4[2 * j + 1];
        float4 cx1 = c4[2 * j + 2];
        float4 cy1 = c4[2 * j + 3];
        float4 cx2 = c4[2 * j + 4];
        float4 cy2 = c4[2 * j + 5];
        float4 cx3 = c4[2 * j + 6];
        float4 cy3 = c4[2 * j + 7];

        float fx0 = fmaf(fmaf(cx0.x, px, cx0.y), px, cx0.z);
        float fy0 = fmaf(fmaf(cy0.x, py, cy0.y), py, cy0.z);
        float fx1 = fmaf(fmaf(cx1.x, px, cx1.y), px, cx1.z);
        float fy1 = fmaf(fmaf(cy1.x, py, cy1.y), py, cy1.z);
        float fx2 = fmaf(fmaf(cx2.x, px, cx2.y), px, cx2.z);
        float fy2 = fmaf(fmaf(cy2.x, py, cy2.y), py, cy2.z);
        float fx3 = fmaf(fmaf(cx3.x, px, cx3.y), px, cx3.z);
        float fy3 = fmaf(fmaf(cy3.x, py, cy3.y), py, cy3.z);

        fx0 = fmaxf(fx0, 0.0f); fy0 = fmaxf(fy0, 0.0f);
        fx1 = fmaxf(fx1, 0.0f); fy1 = fmaxf(fy1, 0.0f);
        fx2 = fmaxf(fx2, 0.0f); fy2 = fmaxf(fy2, 0.0f);
        fx3 = fmaxf(fx3, 0.0f); fy3 = fmaxf(fy3, 0.0f);

        acc0 = fmaxf(acc0, fx0 * fy0);
        acc1 = fmaxf(acc1, fx1 * fy1);
        acc2 = fmaxf(acc2, fx2 * fy2);
        acc3 = fmaxf(acc3, fx3 * fy3);
    }

    float acc = fmaxf(fmaxf(acc0, acc1), fmaxf(acc2, acc3));
    out[i] = sqrtf(acc);
}

extern "C" void kernel_launch(void* const* d_in, const int* in_sizes, int n_in,
                              void* d_out, int out_size, void* d_ws, size_t ws_size,
                              hipStream_t stream) {
    const float* points = (const float*)d_in[0];     // (204800, 2)
    const float* gt_bboxes = (const float*)d_in[1];  // (256, 4)
    // d_in[2] strides: unused by the reference output.
    float* out = (float*)d_out;                      // (204800,)
    float* coef = (float*)d_ws;                      // 256 * 8 floats = 8 KB

    box_coef_kernel<<<1, 256, 0, stream>>>(gt_bboxes, coef);
    centerness_kernel<<<N_POINTS / 256, 256, 0, stream>>>(points, coef, out);
}

// Round 2
// 72.013 us; speedup vs baseline: 1.3663x; 1.3663x over previous
//
#include <hip/hip_runtime.h>

#define N_POINTS 204800
#define N_GT 256
#define BLOCK 256
#define PTS_PER_BLOCK 512  // 2 points per thread

// Fused kernel.
// Math: centerness(p, box) = sqrt(max(l,0)max(r,0)/max(l+r,eps)) * (same for t,b)
//   Since at most one of l,r is negative and l+r = w > 0:
//     max(l,0)*max(r,0)/max(l+r,eps) = max( (px-x1)(x2-px)/w, 0 ) = max(fx, 0)
//   fx is a quadratic in px: fx = a2*px^2 + a1*px + a0 with
//     a2 = -1/w, a1 = (x1+x2)/w, a0 = -x1*x2/w        (same for y with h)
//   sqrt is monotone -> hoist out of the 256-box max: out = sqrt(max_j fx_j*fy_j)
// Coefficients are computed per-block into LDS (one box per thread), then the
// inner loop reads them with uniform-address ds_read_b128 (broadcast, no bank
// conflicts). Each thread processes 2 points to balance LDS vs VALU pipes.
__global__ __launch_bounds__(BLOCK) void centerness_fused_kernel(
    const float* __restrict__ points, const float* __restrict__ gt,
    float* __restrict__ out) {
  __shared__ float4 scoef[2 * N_GT];  // [2j] = x-coefs (a2,a1,a0,0), [2j+1] = y

  const int t = threadIdx.x;

  // --- stage coefficients: thread t handles box t ---
  {
    float4 b = ((const float4*)gt)[t];  // x1,y1,x2,y2 — coalesced 16B
    float iw = 1.0f / (b.z - b.x);
    float ih = 1.0f / (b.w - b.y);
    scoef[2 * t]     = make_float4(-iw, (b.x + b.z) * iw, -(b.x * b.z) * iw, 0.0f);
    scoef[2 * t + 1] = make_float4(-ih, (b.y + b.w) * ih, -(b.y * b.w) * ih, 0.0f);
  }
  __syncthreads();

  // --- 2 points per thread, coalesced ---
  const int base = blockIdx.x * PTS_PER_BLOCK;
  float2 p0 = ((const float2*)points)[base + t];
  float2 p1 = ((const float2*)points)[base + BLOCK + t];

  // 2 accumulators per point (box-parity) -> 4 independent max chains.
  float acc0a = 0.0f, acc0b = 0.0f, acc1a = 0.0f, acc1b = 0.0f;

#pragma unroll 8
  for (int j = 0; j < N_GT; j += 2) {
    float4 cx0 = scoef[2 * j];
    float4 cy0 = scoef[2 * j + 1];
    float4 cx1 = scoef[2 * j + 2];
    float4 cy1 = scoef[2 * j + 3];

    // box j, points 0/1
    float fx00 = fmaf(fmaf(cx0.x, p0.x, cx0.y), p0.x, cx0.z);
    float fy00 = fmaf(fmaf(cy0.x, p0.y, cy0.y), p0.y, cy0.z);
    float fx01 = fmaf(fmaf(cx0.x, p1.x, cx0.y), p1.x, cx0.z);
    float fy01 = fmaf(fmaf(cy0.x, p1.y, cy0.y), p1.y, cy0.z);
    // box j+1, points 0/1
    float fx10 = fmaf(fmaf(cx1.x, p0.x, cx1.y), p0.x, cx1.z);
    float fy10 = fmaf(fmaf(cy1.x, p0.y, cy1.y), p0.y, cy1.z);
    float fx11 = fmaf(fmaf(cx1.x, p1.x, cx1.y), p1.x, cx1.z);
    float fy11 = fmaf(fmaf(cy1.x, p1.y, cy1.y), p1.y, cy1.z);

    fx00 = fmaxf(fx00, 0.0f); fy00 = fmaxf(fy00, 0.0f);
    fx01 = fmaxf(fx01, 0.0f); fy01 = fmaxf(fy01, 0.0f);
    fx10 = fmaxf(fx10, 0.0f); fy10 = fmaxf(fy10, 0.0f);
    fx11 = fmaxf(fx11, 0.0f); fy11 = fmaxf(fy11, 0.0f);

    acc0a = fmaxf(acc0a, fx00 * fy00);
    acc0b = fmaxf(acc0b, fx10 * fy10);
    acc1a = fmaxf(acc1a, fx01 * fy01);
    acc1b = fmaxf(acc1b, fx11 * fy11);
  }

  out[base + t]         = sqrtf(fmaxf(acc0a, acc0b));
  out[base + BLOCK + t] = sqrtf(fmaxf(acc1a, acc1b));
}

extern "C" void kernel_launch(void* const* d_in, const int* in_sizes, int n_in,
                              void* d_out, int out_size, void* d_ws, size_t ws_size,
                              hipStream_t stream) {
  const float* points = (const float*)d_in[0];     // (204800, 2)
  const float* gt_bboxes = (const float*)d_in[1];  // (256, 4)
  // d_in[2] strides: unused by the reference output.
  float* out = (float*)d_out;                      // (204800,)

  centerness_fused_kernel<<<N_POINTS / PTS_PER_BLOCK, BLOCK, 0, stream>>>(
      points, gt_bboxes, out);
}